// Round 2
// 791.120 us; speedup vs baseline: 1.0376x; 1.0376x over previous
//
#include <hip/hip_runtime.h>
#include <hip/hip_bf16.h>
#include <cstdint>
#include <cstddef>

using bf16 = __hip_bfloat16;
typedef __attribute__((ext_vector_type(8))) short bf16x8;
typedef __attribute__((ext_vector_type(4))) float floatx4;

#define GLOBAL_AS __attribute__((address_space(1)))
#define LDS_AS    __attribute__((address_space(3)))

__device__ __forceinline__ void async_copy16(void* lds, const void* g) {
    __builtin_amdgcn_global_load_lds((GLOBAL_AS void*)(g), (LDS_AS void*)(lds), 16, 0, 0);
}

__device__ __forceinline__ floatx4 mfma_bf16(bf16x8 a, bf16x8 b, floatx4 c) {
    return __builtin_amdgcn_mfma_f32_16x16x32_bf16(a, b, c, 0, 0, 0);
}

// fp32 -> bf16 elementwise, 4 elements/thread. n must be a multiple of 4.
__global__ void cvt_f32_bf16(const float* __restrict__ src, bf16* __restrict__ dst, int n) {
    int i = (blockIdx.x * blockDim.x + threadIdx.x) * 4;
    if (i < n) {
        float4 v = *(const float4*)(src + i);
        __align__(8) bf16 t[4];
        t[0] = __float2bfloat16(v.x);
        t[1] = __float2bfloat16(v.y);
        t[2] = __float2bfloat16(v.z);
        t[3] = __float2bfloat16(v.w);
        *(short4*)(dst + i) = *(const short4*)t;
    }
}

// C[m,n] = sum_k A[m,k] * W[n,k] + bias[n].   (bias is fp32)
// OUTF==0: C bf16 [M][N] row-major; OUTF==1: C fp32 [M][N] row-major.
template <int OUTF>
__global__ __launch_bounds__(256, 3) void gemm_bt_bias(
    const bf16* __restrict__ A, const bf16* __restrict__ W,
    const float* __restrict__ bias, void* __restrict__ Cv,
    int M, int N, int K)
{
    __shared__ __align__(16) bf16 As[128 * 32];
    __shared__ __align__(16) bf16 Ws[128 * 32];

    const int tid  = threadIdx.x;
    const int lane = tid & 63;
    const int wave = tid >> 6;
    const int quad = lane >> 4;
    const int l16  = lane & 15;
    const int wm = (wave >> 1) * 64;
    const int wn = (wave & 1) * 64;

    const int bm = blockIdx.x;
    const int bn = blockIdx.y;

    floatx4 acc[4][4];
#pragma unroll
    for (int i = 0; i < 4; ++i)
#pragma unroll
        for (int j = 0; j < 4; ++j) acc[i][j] = (floatx4){0.f, 0.f, 0.f, 0.f};

    const int srow = tid >> 2;
    const int scol = (tid & 3) * 8;
    const bf16* gA = A + (size_t)(bm * 128 + srow) * K + scol;
    const bf16* gW = W + (size_t)(bn * 128 + srow) * K + scol;
    bf16* lA0 = As + tid * 8;
    bf16* lA1 = As + 2048 + tid * 8;
    bf16* lW0 = Ws + tid * 8;
    bf16* lW1 = Ws + 2048 + tid * 8;
    const size_t skip = (size_t)64 * K;

    const int kt_n = K >> 5;
    for (int kt = 0; kt < kt_n; ++kt) {
        __syncthreads();
        const bf16* ga = gA + kt * 32;
        const bf16* gw = gW + kt * 32;
        async_copy16(lA0, ga);
        async_copy16(lA1, ga + skip);
        async_copy16(lW0, gw);
        async_copy16(lW1, gw + skip);
        __syncthreads();

        bf16x8 af[4], bfr[4];
#pragma unroll
        for (int mi = 0; mi < 4; ++mi)
            af[mi] = *(const bf16x8*)(As + (wm + mi * 16 + l16) * 32 + quad * 8);
#pragma unroll
        for (int ni = 0; ni < 4; ++ni)
            bfr[ni] = *(const bf16x8*)(Ws + (wn + ni * 16 + l16) * 32 + quad * 8);
#pragma unroll
        for (int mi = 0; mi < 4; ++mi)
#pragma unroll
            for (int ni = 0; ni < 4; ++ni)
                acc[mi][ni] = mfma_bf16(af[mi], bfr[ni], acc[mi][ni]);
    }

#pragma unroll
    for (int mi = 0; mi < 4; ++mi) {
        const int row0 = bm * 128 + wm + mi * 16 + quad * 4;
#pragma unroll
        for (int ni = 0; ni < 4; ++ni) {
            const int col = bn * 128 + wn + ni * 16 + l16;
            const float bv = bias[col];
            if (OUTF) {
                float* C = (float*)Cv;
#pragma unroll
                for (int r = 0; r < 4; ++r)
                    C[(size_t)(row0 + r) * N + col] = acc[mi][ni][r] + bv;
            } else {
                bf16* C = (bf16*)Cv;
#pragma unroll
                for (int r = 0; r < 4; ++r)
                    C[(size_t)(row0 + r) * N + col] = __float2bfloat16(acc[mi][ni][r] + bv);
            }
        }
    }
}

// Fused K+V projection. Logical N=2048: bn<8 -> K rows (k_buf row-major
// [M][1024] bf16); bn>=8 -> V rows (vt [B][1024][T] transposed bf16 store).
__global__ __launch_bounds__(256, 3) void gemm_kv(
    const bf16* __restrict__ A,
    const bf16* __restrict__ Wk, const bf16* __restrict__ Wv,
    const float* __restrict__ bk, const float* __restrict__ bv,
    bf16* __restrict__ kout, bf16* __restrict__ vt,
    int M, int K)
{
    __shared__ __align__(16) bf16 As[128 * 32];
    __shared__ __align__(16) bf16 Ws[128 * 32];

    const int tid  = threadIdx.x;
    const int lane = tid & 63;
    const int wave = tid >> 6;
    const int quad = lane >> 4;
    const int l16  = lane & 15;
    const int wm = (wave >> 1) * 64;
    const int wn = (wave & 1) * 64;

    const int bm = blockIdx.x;
    const int bn = blockIdx.y;
    const bool isK = (bn < 8);
    const int nb = isK ? bn : (bn - 8);
    const bf16* Wsel  = isK ? Wk : Wv;
    const float* bsel = isK ? bk : bv;

    floatx4 acc[4][4];
#pragma unroll
    for (int i = 0; i < 4; ++i)
#pragma unroll
        for (int j = 0; j < 4; ++j) acc[i][j] = (floatx4){0.f, 0.f, 0.f, 0.f};

    const int srow = tid >> 2;
    const int scol = (tid & 3) * 8;
    const bf16* gA = A    + (size_t)(bm * 128 + srow) * K + scol;
    const bf16* gW = Wsel + (size_t)(nb * 128 + srow) * K + scol;
    bf16* lA0 = As + tid * 8;
    bf16* lA1 = As + 2048 + tid * 8;
    bf16* lW0 = Ws + tid * 8;
    bf16* lW1 = Ws + 2048 + tid * 8;
    const size_t skip = (size_t)64 * K;

    const int kt_n = K >> 5;
    for (int kt = 0; kt < kt_n; ++kt) {
        __syncthreads();
        const bf16* ga = gA + kt * 32;
        const bf16* gw = gW + kt * 32;
        async_copy16(lA0, ga);
        async_copy16(lA1, ga + skip);
        async_copy16(lW0, gw);
        async_copy16(lW1, gw + skip);
        __syncthreads();

        bf16x8 af[4], bfr[4];
#pragma unroll
        for (int mi = 0; mi < 4; ++mi)
            af[mi] = *(const bf16x8*)(As + (wm + mi * 16 + l16) * 32 + quad * 8);
#pragma unroll
        for (int ni = 0; ni < 4; ++ni)
            bfr[ni] = *(const bf16x8*)(Ws + (wn + ni * 16 + l16) * 32 + quad * 8);
#pragma unroll
        for (int mi = 0; mi < 4; ++mi)
#pragma unroll
            for (int ni = 0; ni < 4; ++ni)
                acc[mi][ni] = mfma_bf16(af[mi], bfr[ni], acc[mi][ni]);
    }

#pragma unroll
    for (int mi = 0; mi < 4; ++mi) {
        const int row0 = bm * 128 + wm + mi * 16 + quad * 4;
#pragma unroll
        for (int ni = 0; ni < 4; ++ni) {
            const int col = nb * 128 + wn + ni * 16 + l16;
            const float bvv = bsel[col];
            if (isK) {
#pragma unroll
                for (int r = 0; r < 4; ++r)
                    kout[(size_t)(row0 + r) * 1024 + col] = __float2bfloat16(acc[mi][ni][r] + bvv);
            } else {
                __align__(8) bf16 tmp[4];
#pragma unroll
                for (int r = 0; r < 4; ++r) tmp[r] = __float2bfloat16(acc[mi][ni][r] + bvv);
                const int b  = row0 >> 11;      // T = 2048
                const int t0 = row0 & 2047;
                bf16* dst = vt + ((size_t)(b * 1024 + col)) * 2048 + t0;
                *(short4*)dst = *(const short4*)tmp;
            }
        }
    }
}

// Flash attention, causal, balanced q-tile pairing.
// Block (qi, bh) handles q-tiles qtB=31-qi (large) and qtA=qi (small).
// v6: latency-hiding rewrite, defensive barrier form.
//  - Q fragments live in registers (loaded once; frees 35KB LDS).
//  - K/V double-buffered in LDS via global_load_lds DMA. Next tile's 8
//    loads/thread are issued at the TOP of the iteration; the compute
//    phase of the current tile (~32 MFMA + softmax) hides the L2 latency;
//    the end-of-iteration __syncthreads() (which drains vmcnt/lgkmcnt)
//    guarantees the prefetch landed and all reads of the old buffer are
//    done before it is overwritten. Only block-uniform compiler barriers
//    -> no deadlock risk, no inline-asm scheduling hazards.
//  - Linear LDS destination (wave-uniform base + lane*16B, as DMA
//    requires) + XOR-preswizzled GLOBAL source column + the same XOR on
//    the ds_read side (both-sides-or-neither), so b128 reads hit the
//    8-cycle bank minimum despite power-of-2 row strides.
__global__ __launch_bounds__(256, 2) void attn_fwd(
    const bf16* __restrict__ qb, const bf16* __restrict__ kb,
    const bf16* __restrict__ vtb, bf16* __restrict__ ob)
{
    constexpr int T  = 2048;
    constexpr int DQ = 4096;
    constexpr int DK = 1024;

    __shared__ __align__(16) bf16 Ks[2][64 * 128];   // [buf][row 0..63][col granule], linear
    __shared__ __align__(16) bf16 Vs[2][128 * 64];   // [buf][d 0..127][s granule], linear
    __shared__ __align__(16) bf16 Ps[4][16][72];     // per-wave P tile

    const int tid  = threadIdx.x;
    const int lane = tid & 63;
    const int wave = tid >> 6;
    const int quad = lane >> 4;
    const int l16  = lane & 15;
    const int swz  = l16 & 7;

    const int qi = blockIdx.x;    // 0..15
    const int bh = blockIdx.y;
    const int b  = bh >> 5;
    const int h  = bh & 31;
    const int g  = h >> 2;        // GROUP = 4
    const int qtB = 31 - qi;      // large tile
    const int qtA = qi;           // small tile
    const int q0B = qtB * 64;
    const int q0A = qtA * 64;
    const int qw = wave * 16;

    const bf16* Qg = qb  + (size_t)b * T * DQ + (size_t)h * 128;
    const bf16* Kg = kb  + (size_t)b * T * DK + (size_t)g * 128;
    const bf16* Vg = vtb + ((size_t)b * DK + g * 128) * T;
    bf16*       Og = ob  + (size_t)b * T * DQ + (size_t)h * 128;

    // ---- Q fragments -> registers (16 q-rows per wave per tile) ----
    bf16x8 qf[2][4];
    {
        const size_t rB = (size_t)(q0B + qw + l16) * DQ;
        const size_t rA = (size_t)(q0A + qw + l16) * DQ;
#pragma unroll
        for (int kk = 0; kk < 4; ++kk) {
            qf[0][kk] = *(const bf16x8*)(Qg + rB + kk * 32 + quad * 8);
            qf[1][kk] = *(const bf16x8*)(Qg + rA + kk * 32 + quad * 8);
        }
    }

    // staging geometry (per-thread, 16B granules)
    const int krow_l = tid >> 4;   // K tile: row = i*16 + krow_l, col16 = tid&15
    const int kc16   = tid & 15;
    const int vrow_l = tid >> 3;   // V tile: row = i*32 + vrow_l, col16 = tid&7
    const int vc16   = tid & 7;

    // Stage tile st_ into buffer bi_: 8 global_load_lds per thread.
    // LDS dest is LINEAR (base + lane*16B per wave); global source column
    // is pre-swizzled with (row & 7).
    auto STAGE = [&](int st_, int bi_) {
        const int s0_ = st_ * 64;
        bf16* kbp = &Ks[bi_][0];
        bf16* vbp = &Vs[bi_][0];
#pragma unroll
        for (int i = 0; i < 4; ++i) {
            const int r = i * 16 + krow_l;
            async_copy16(kbp + (i * 256 + tid) * 8,
                         Kg + (size_t)(s0_ + r) * DK + ((kc16 ^ (r & 7)) * 8));
        }
#pragma unroll
        for (int i = 0; i < 4; ++i) {
            const int r = i * 32 + vrow_l;
            async_copy16(vbp + (i * 256 + tid) * 8,
                         Vg + (size_t)r * T + s0_ + ((vc16 ^ (r & 7)) * 8));
        }
    };

    floatx4 oacc[2][8];
#pragma unroll
    for (int t = 0; t < 2; ++t)
#pragma unroll
        for (int i = 0; i < 8; ++i) oacc[t][i] = (floatx4){0.f, 0.f, 0.f, 0.f};
    float m_run[2][4], l_run[2][4];
#pragma unroll
    for (int t = 0; t < 2; ++t)
#pragma unroll
        for (int r = 0; r < 4; ++r) { m_run[t][r] = -1e30f; l_run[t][r] = 0.f; }

    const float scale = 0.08838834764831845f;  // 1/sqrt(128)

    STAGE(0, 0);
    __syncthreads();   // drains vmcnt: tile 0 resident in LDS for all waves

    for (int st = 0; st <= qtB; ++st) {
        const int bi = st & 1;
        const int s0 = st * 64;

        if (st < qtB) STAGE(st + 1, bi ^ 1);   // prefetch next tile into other buffer

        const bf16* Kb = &Ks[bi][0];
        const bf16* Vb = &Vs[bi][0];

        const int ntile = (st <= qtA) ? 2 : 1;
#pragma unroll
        for (int t = 0; t < 2; ++t) {
            if (t >= ntile) break;
            const int q0t  = t ? q0A : q0B;
            const int qt_t = t ? qtA : qtB;

            // S[16q][64s] for this tile
            floatx4 sacc[4];
#pragma unroll
            for (int i = 0; i < 4; ++i) sacc[i] = (floatx4){0.f, 0.f, 0.f, 0.f};
#pragma unroll
            for (int kk = 0; kk < 4; ++kk) {
                const int koff = ((kk * 4 + quad) ^ swz) * 8;
#pragma unroll
                for (int ni = 0; ni < 4; ++ni) {
                    bf16x8 bk8 = *(const bf16x8*)(Kb + (ni * 16 + l16) * 128 + koff);
                    sacc[ni] = mfma_bf16(qf[t][kk], bk8, sacc[ni]);
                }
            }

            const bool diag = (st == qt_t);
#pragma unroll
            for (int r = 0; r < 4; ++r) {
                const int qg = q0t + qw + quad * 4 + r;   // C/D row = quad*4+reg
                float sv[4];
#pragma unroll
                for (int ni = 0; ni < 4; ++ni) {
                    float x = sacc[ni][r] * scale;
                    if (diag && (s0 + ni * 16 + l16) > qg) x = -1e30f;
                    sv[ni] = x;
                }
                float mx = fmaxf(fmaxf(sv[0], sv[1]), fmaxf(sv[2], sv[3]));
                mx = fmaxf(mx, __shfl_xor(mx, 1, 64));
                mx = fmaxf(mx, __shfl_xor(mx, 2, 64));
                mx = fmaxf(mx, __shfl_xor(mx, 4, 64));
                mx = fmaxf(mx, __shfl_xor(mx, 8, 64));
                const float mnew  = fmaxf(m_run[t][r], mx);
                const float alpha = __expf(m_run[t][r] - mnew);
                float ssum = 0.f;
#pragma unroll
                for (int ni = 0; ni < 4; ++ni) {
                    float p = __expf(sv[ni] - mnew);
                    ssum += p;
                    Ps[wave][quad * 4 + r][ni * 16 + l16] = __float2bfloat16(p);
                }
                ssum += __shfl_xor(ssum, 1, 64);
                ssum += __shfl_xor(ssum, 2, 64);
                ssum += __shfl_xor(ssum, 4, 64);
                ssum += __shfl_xor(ssum, 8, 64);
                l_run[t][r] = l_run[t][r] * alpha + ssum;
                m_run[t][r] = mnew;
#pragma unroll
                for (int db = 0; db < 8; ++db) oacc[t][db][r] *= alpha;
            }
            asm volatile("s_waitcnt lgkmcnt(0)" ::: "memory");

            // O += P @ V
#pragma unroll
            for (int kk = 0; kk < 2; ++kk) {
                bf16x8 ap = *(const bf16x8*)&Ps[wave][l16][kk * 32 + quad * 8];
                const int voff = ((kk * 4 + quad) ^ swz) * 8;
#pragma unroll
                for (int db = 0; db < 8; ++db) {
                    bf16x8 bv8 = *(const bf16x8*)(Vb + (db * 16 + l16) * 64 + voff);
                    oacc[t][db] = mfma_bf16(ap, bv8, oacc[t][db]);
                }
            }
        }

        // Drains vmcnt(0)+lgkmcnt(0) then barriers: prefetch for tile st+1
        // has landed, and every wave is done reading buf[bi] before the
        // next iteration's STAGE overwrites it.
        __syncthreads();
    }

#pragma unroll
    for (int t = 0; t < 2; ++t) {
        const int q0t = t ? q0A : q0B;
#pragma unroll
        for (int r = 0; r < 4; ++r) {
            const float inv = 1.0f / l_run[t][r];
            const int qg = q0t + qw + quad * 4 + r;
#pragma unroll
            for (int db = 0; db < 8; ++db)
                Og[(size_t)qg * DQ + db * 16 + l16] = __float2bfloat16(oacc[t][db][r] * inv);
        }
    }
}

extern "C" void kernel_launch(void* const* d_in, const int* in_sizes, int n_in,
                              void* d_out, int out_size, void* d_ws, size_t ws_size,
                              hipStream_t stream)
{
    const float* hs = (const float*)d_in[0];
    const float* Wq = (const float*)d_in[1];
    const float* bq = (const float*)d_in[2];
    const float* Wk = (const float*)d_in[3];
    const float* bk = (const float*)d_in[4];
    const float* Wv = (const float*)d_in[5];
    const float* bv = (const float*)d_in[6];
    const float* Wo = (const float*)d_in[7];
    const float* bo = (const float*)d_in[8];
    float* out = (float*)d_out;

    const int M  = 4096;         // B*T tokens
    const int D  = 4096;
    const int DK = 1024;         // G*d
    const size_t SZ_D  = (size_t)M * D;
    const size_t SZ_K  = (size_t)M * DK;

    bf16* hsb  = (bf16*)d_ws;            // [M][D]
    bf16* Wqb  = hsb  + SZ_D;            // [D][D]
    bf16* Wkb  = Wqb  + SZ_D;            // [DK][D]
    bf16* Wvb  = Wkb  + SZ_K;            // [DK][D]
    bf16* Wob  = Wvb  + SZ_K;            // [D][D]
    bf16* q_buf = Wob + SZ_D;            // [M][D]
    bf16* k_buf = q_buf + SZ_D;          // [M][DK]
    bf16* vt_buf = Wqb;                  // ALIAS: Wq consumed before KV-gemm writes vt
    bf16* o_buf  = hsb;                  // ALIAS: hs consumed before attn writes o

    dim3 blk(256);
    const int CB = 256;
    cvt_f32_bf16<<<(int)(SZ_D / 4 + CB - 1) / CB, CB, 0, stream>>>(hs, hsb, (int)SZ_D);
    cvt_f32_bf16<<<(int)(SZ_D / 4 + CB - 1) / CB, CB, 0, stream>>>(Wq, Wqb, (int)SZ_D);
    cvt_f32_bf16<<<(int)(SZ_K / 4 + CB - 1) / CB, CB, 0, stream>>>(Wk, Wkb, (int)SZ_K);
    cvt_f32_bf16<<<(int)(SZ_K / 4 + CB - 1) / CB, CB, 0, stream>>>(Wv, Wvb, (int)SZ_K);
    cvt_f32_bf16<<<(int)(SZ_D / 4 + CB - 1) / CB, CB, 0, stream>>>(Wo, Wob, (int)SZ_D);

    gemm_bt_bias<0><<<dim3(M / 128, D / 128), blk, 0, stream>>>(hsb, Wqb, bq, q_buf, M, D, D);
    gemm_kv<<<dim3(M / 128, 16), blk, 0, stream>>>(hsb, Wkb, Wvb, bk, bv, k_buf, vt_buf, M, D);
    attn_fwd<<<dim3(16, 64), blk, 0, stream>>>(q_buf, k_buf, vt_buf, o_buf);
    gemm_bt_bias<1><<<dim3(M / 128, D / 128), blk, 0, stream>>>(o_buf, Wob, bo, out, M, D, D);
}